// Round 8
// baseline (1087.178 us; speedup 1.0000x reference)
//
#include <hip/hip_runtime.h>
#include <cstdint>
#include <cstddef>

namespace {

constexpr int Bb = 8;
constexpr int Nn = 2048;
constexpr int Dd = 1024;
constexpr int NT = 64;  // kv tiles of 32

typedef _Float16 half8 __attribute__((ext_vector_type(8)));
typedef float f32x4v __attribute__((ext_vector_type(4)));
typedef float f32x16v __attribute__((ext_vector_type(16)));
typedef unsigned int v2u __attribute__((ext_vector_type(2)));
typedef unsigned int v4u __attribute__((ext_vector_type(4)));

__device__ __forceinline__ float fast_exp2(float x) {
  float r;
  asm("v_exp_f32 %0, %1\n\ts_nop 1" : "=v"(r) : "v"(x));
  return r;
}

// pack two f32 -> one u32 of 2x fp16 (RTZ); src0 -> low 16 bits
__device__ __forceinline__ unsigned cvt2(float a, float b) {
  return __builtin_bit_cast(unsigned, __builtin_amdgcn_cvt_pkrtz(a, b));
}

__device__ __forceinline__ void barrier_lgkm() {
  asm volatile("s_waitcnt lgkmcnt(0)" ::: "memory");
  __builtin_amdgcn_s_barrier();
  __builtin_amdgcn_sched_barrier(0);
}

// fp32 -> packed fp16 stream (same element order, 2B/elem)
__global__ void convf16(const float* __restrict__ in, v4u* __restrict__ out) {
  const int n8 = Bb * Nn * Dd / 8;
  int i = blockIdx.x * blockDim.x + threadIdx.x;
  const int stride = gridDim.x * blockDim.x;
  const f32x4v* in4 = (const f32x4v*)in;
  for (; i < n8; i += stride) {
    f32x4v a = in4[2 * i], b = in4[2 * i + 1];
    v4u p;
    p[0] = cvt2(a[0], a[1]);
    p[1] = cvt2(a[2], a[3]);
    p[2] = cvt2(b[0], b[1]);
    p[3] = cvt2(b[2], b[3]);
    out[i] = p;
  }
}

template <int WS>
__device__ __forceinline__ v4u ld8h(const float* f32p, const v4u* h16p) {
  if constexpr (WS) {
    return *h16p;
  } else {
    f32x4v a = *(const f32x4v*)f32p;
    f32x4v b = *(const f32x4v*)(f32p + 4);
    v4u p;
    p[0] = cvt2(a[0], a[1]);
    p[1] = cvt2(a[2], a[3]);
    p[2] = cvt2(b[0], b[1]);
    p[3] = cvt2(b[2], b[3]);
    return p;
  }
}

// Flash attention fwd (no scale), K == V == Y. 512 threads = 8 waves:
// wave = (kvf in 0..1) x (ds in 0..3, 256-d slice). QB=32, KVB=32.
// 2-barrier pipelined schedule:
//  phase1: LOADY(t+1) | PV-issue(t-1) | S-MFMA(t) | pscr wr | PV-MFMA(t-1) [B]
//  phase2: softmax(t) (waves 0,1) | stage ybuf <- tile t                   [A]
template <int WS>
__global__ __launch_bounds__(512, 2) void flash_fwd(
    const float* __restrict__ Qf, const float* __restrict__ Yf,
    const v4u* __restrict__ Qw, const v4u* __restrict__ Yw,
    float* __restrict__ Om) {
  // ybuf tr-window layout:
  // addr(kv,d) = (kv>>2)*8192 + (d>>4)*128 + (kv&3)*32 + (d&15)*2
  __shared__ __attribute__((aligned(128))) char ybuf[65536];
  __shared__ __attribute__((aligned(16))) char pscr[16384];
  __shared__ __attribute__((aligned(16))) char Pb[2048];  // [oct][q] 16B
  __shared__ float sscale[32];
  __shared__ float sinvl[32];
  __shared__ int sflag[2];

  const int tid = (int)threadIdx.x;
  const int w = tid >> 6, l = tid & 63;
  const int lm = l & 15, g = (l >> 4) & 3, g2 = (l >> 5) & 1, l31 = l & 31;
  const int kvf = w >> 2, ds = w & 3;
  const int bid = (int)blockIdx.x, batch = bid & 7, row0 = (bid >> 3) * 32;
  const size_t bY = (size_t)batch * Nn;

  // ---- Q fragments (B-operand): lane(lm,g): q = qh*16+lm,
  // d = ds*256 + ks*32 + g*8 + i   (ks = 0..7)
  v4u qreg[2][8];
#pragma unroll
  for (int qh = 0; qh < 2; ++qh)
#pragma unroll
    for (int ks = 0; ks < 8; ++ks) {
      const int rr = row0 + qh * 16 + lm;
      const int dd_ = ds * 256 + ks * 32 + g * 8;
      qreg[qh][ks] = ld8h<WS>(Qf + (size_t)(bY + rr) * Dd + dd_,
                              Qw + (size_t)(bY + rr) * 128 + (dd_ >> 3));
    }

#define LOADY(dst, t_)                                                        \
  do {                                                                        \
    const int rr_ = (t_)*32 + kvf * 16 + lm;                                  \
    _Pragma("unroll") for (int ks = 0; ks < 8; ++ks) {                        \
      const int dd_ = ds * 256 + ks * 32 + g * 8;                             \
      dst[ks] = ld8h<WS>(Yf + (size_t)(bY + rr_) * Dd + dd_,                  \
                         Yw + (size_t)(bY + rr_) * 128 + (dd_ >> 3));         \
    }                                                                         \
  } while (0)

  // staging write: lane(lm,g) kv=kvf*16+lm, d=ds*256+ks*32+g*8 (16B half-row)
  const unsigned sbase =
      (unsigned)((kvf * 4 + (lm >> 2)) * 8192 + (ds * 16 + (g >> 1)) * 128 +
                 (lm & 3) * 32 + (g & 1) * 16);
#define STAGE_WR(SRC)                                                         \
  do {                                                                        \
    _Pragma("unroll") for (int ks = 0; ks < 8; ++ks)                          \
        *(v4u*)(ybuf + sbase + ks * 256) = SRC[ks];                           \
  } while (0)

  v4u sA[8], sB[8];
  LOADY(sA, 0);

  f32x16v Oacc[4];
#pragma unroll
  for (int i = 0; i < 4; ++i)
#pragma unroll
    for (int j = 0; j < 16; ++j) Oacc[i][j] = 0.0f;

  float m_run = -__builtin_inff();
  float l_run = 0.0f;
  const unsigned ylds = (unsigned)(uintptr_t)&ybuf[0];
  constexpr float L2E = 1.44269504088896f;

  half8 pa0, pa1;
  v2u trr[16];

  // PV-issue: read P fragments + issue all 16 tr reads (no wait).
#define PV_ISSUE()                                                            \
  do {                                                                        \
    pa0 = *(const half8*)(Pb + g2 * 512 + l31 * 16);                          \
    pa1 = *(const half8*)(Pb + (2 + g2) * 512 + l31 * 16);                    \
    _Pragma("unroll") for (int kb = 0; kb < 2; ++kb)                          \
        _Pragma("unroll") for (int df = 0; df < 4; ++df) {                    \
      const unsigned wb =                                                     \
          ylds + (unsigned)((kb * 4 + g2 * 2) * 8192 +                        \
                            ((w * 4 + df) * 2 + (l31 >> 4)) * 128 +           \
                            (l31 & 15) * 8);                                  \
      asm volatile("ds_read_b64_tr_b16 %0, %1"                                \
                   : "=v"(trr[kb * 8 + df * 2])                               \
                   : "v"(wb));                                                \
      asm volatile("ds_read_b64_tr_b16 %0, %1"                                \
                   : "=v"(trr[kb * 8 + df * 2 + 1])                           \
                   : "v"(wb + 8192u));                                        \
    }                                                                         \
  } while (0)

  // PV-finish: rescale Oacc, wait for tr reads, run PV MFMAs.
#define PV_FINISH()                                                           \
  do {                                                                        \
    if (sflag[0] | sflag[1]) {                                                \
      _Pragma("unroll") for (int df = 0; df < 4; ++df)                        \
          _Pragma("unroll") for (int r = 0; r < 16; ++r) {                    \
        const int q_ = (r & 3) + 8 * (r >> 2) + 4 * g2;                       \
        Oacc[df][r] *= sscale[q_];                                            \
      }                                                                       \
    }                                                                         \
    asm volatile("s_waitcnt lgkmcnt(0)" ::: "memory");                        \
    __builtin_amdgcn_sched_barrier(0);                                        \
    _Pragma("unroll") for (int kb = 0; kb < 2; ++kb)                          \
        _Pragma("unroll") for (int df = 0; df < 4; ++df) {                    \
      v4u bu;                                                                 \
      bu[0] = trr[kb * 8 + df * 2][0];                                        \
      bu[1] = trr[kb * 8 + df * 2][1];                                        \
      bu[2] = trr[kb * 8 + df * 2 + 1][0];                                    \
      bu[3] = trr[kb * 8 + df * 2 + 1][1];                                    \
      Oacc[df] = __builtin_amdgcn_mfma_f32_32x32x16_f16(                      \
          kb ? pa1 : pa0, __builtin_bit_cast(half8, bu), Oacc[df], 0, 0, 0);  \
    }                                                                         \
  } while (0)

#define TILE_BODY(CUR, NXT, t_, DOPV)                                         \
  do {                                                                        \
    LOADY(NXT, ((t_) + 1) & 63);                                              \
    if (DOPV) PV_ISSUE();                                                     \
    f32x4v acc0 = {0.f, 0.f, 0.f, 0.f}, acc1 = {0.f, 0.f, 0.f, 0.f};          \
    _Pragma("unroll") for (int ks = 0; ks < 8; ++ks) {                        \
      half8 av = __builtin_bit_cast(half8, CUR[ks]);                          \
      acc0 = __builtin_amdgcn_mfma_f32_16x16x32_f16(                          \
          av, __builtin_bit_cast(half8, qreg[0][ks]), acc0, 0, 0, 0);         \
      acc1 = __builtin_amdgcn_mfma_f32_16x16x32_f16(                          \
          av, __builtin_bit_cast(half8, qreg[1][ks]), acc1, 0, 0, 0);         \
    }                                                                         \
    *(f32x4v*)(pscr + (w * 2 + 0) * 1024 + l * 16) = acc0;                    \
    *(f32x4v*)(pscr + (w * 2 + 1) * 1024 + l * 16) = acc1;                    \
    if (DOPV) PV_FINISH();                                                    \
    barrier_lgkm(); /* B: pscr(t) visible; PV/ybuf reads done */              \
    if (w < 2) {                                                              \
      const int qh = w;                                                       \
      f32x4v sa = {0.f, 0.f, 0.f, 0.f}, sb = {0.f, 0.f, 0.f, 0.f};            \
      _Pragma("unroll") for (int s = 0; s < 4; ++s) {                         \
        sa += *(const f32x4v*)(pscr + (s * 2 + qh) * 1024 + l * 16);          \
        sb += *(const f32x4v*)(pscr + ((s + 4) * 2 + qh) * 1024 + l * 16);    \
      }                                                                       \
      float pm = fmaxf(fmaxf(fmaxf(sa[0], sa[1]), fmaxf(sa[2], sa[3])),       \
                       fmaxf(fmaxf(sb[0], sb[1]), fmaxf(sb[2], sb[3])));      \
      pm = fmaxf(pm, __shfl_xor(pm, 16));                                     \
      pm = fmaxf(pm, __shfl_xor(pm, 32));                                     \
      bool defer = (pm <= m_run + 8.0f);                                      \
      bool allw = (bool)__all((int)defer);                                    \
      float scale = 1.0f;                                                     \
      if (!allw) {                                                            \
        float mn = fmaxf(m_run, pm);                                          \
        scale = fast_exp2((m_run - mn) * L2E);                                \
        m_run = mn;                                                           \
      }                                                                       \
      f32x4v ea, eb;                                                          \
      _Pragma("unroll") for (int i = 0; i < 4; ++i) {                         \
        ea[i] = fast_exp2((sa[i] - m_run) * L2E);                             \
        eb[i] = fast_exp2((sb[i] - m_run) * L2E);                             \
      }                                                                       \
      float ps = (ea[0] + ea[1]) + (ea[2] + ea[3]) + (eb[0] + eb[1]) +        \
                 (eb[2] + eb[3]);                                             \
      ps += __shfl_xor(ps, 16);                                               \
      ps += __shfl_xor(ps, 32);                                               \
      l_run = l_run * scale + ps;                                             \
      const int q_ = qh * 16 + lm;                                            \
      v2u pw0, pw1;                                                           \
      pw0[0] = cvt2(ea[0], ea[1]);                                            \
      pw0[1] = cvt2(ea[2], ea[3]);                                            \
      pw1[0] = cvt2(eb[0], eb[1]);                                            \
      pw1[1] = cvt2(eb[2], eb[3]);                                            \
      *(v2u*)(Pb + (g >> 1) * 512 + q_ * 16 + (g & 1) * 8) = pw0;             \
      *(v2u*)(Pb + (2 + (g >> 1)) * 512 + q_ * 16 + (g & 1) * 8) = pw1;       \
      if (l < 16) sscale[q_] = scale;                                         \
      if (l == 0) sflag[qh] = allw ? 0 : 1;                                   \
    }                                                                         \
    STAGE_WR(CUR);                                                            \
    barrier_lgkm(); /* A: ybuf(t) + P(t) + stats visible */                   \
  } while (0)

  TILE_BODY(sA, sB, 0, 0);
  TILE_BODY(sB, sA, 1, 1);
  for (int t = 2; t < NT; t += 2) {
    TILE_BODY(sA, sB, t, 1);
    TILE_BODY(sB, sA, t + 1, 1);
  }
  // final tile's PV (t = 63)
  PV_ISSUE();
  PV_FINISH();

  // ---- epilogue
  if (w < 2 && l < 16) sinvl[w * 16 + lm] = 1.0f / l_run;
  __syncthreads();
#pragma unroll
  for (int df = 0; df < 4; ++df)
#pragma unroll
    for (int r = 0; r < 16; ++r) {
      const int q_ = (r & 3) + 8 * (r >> 2) + 4 * g2;
      const float inv = sinvl[q_];
      Om[(size_t)(bY + row0 + q_) * Dd + (w * 4 + df) * 32 + l31] =
          Oacc[df][r] * inv;
    }
#undef TILE_BODY
#undef PV_FINISH
#undef PV_ISSUE
#undef STAGE_WR
#undef LOADY
}

}  // namespace

extern "C" void kernel_launch(void* const* d_in, const int* in_sizes, int n_in,
                              void* d_out, int out_size, void* d_ws,
                              size_t ws_size, hipStream_t stream) {
  (void)in_sizes; (void)n_in; (void)out_size;
  const float* x = (const float*)d_in[0];
  const float* y = (const float*)d_in[1];
  float* A = (float*)d_out;
  float* Bo = A + (size_t)Bb * Nn * Dd;
  const size_t halfws = (size_t)Bb * Nn * Dd * 2;  // 32 MiB per matrix
  dim3 fg(512), fb(512);
  if (d_ws != nullptr && ws_size >= 2 * halfws) {
    v4u* Xw = (v4u*)d_ws;
    v4u* Yw = (v4u*)((char*)d_ws + halfws);
    hipLaunchKernelGGL(convf16, dim3(2048), dim3(256), 0, stream, x, Xw);
    hipLaunchKernelGGL(convf16, dim3(2048), dim3(256), 0, stream, y, Yw);
    hipLaunchKernelGGL(flash_fwd<1>, fg, fb, 0, stream, x, y, Xw, Yw, A);
    hipLaunchKernelGGL(flash_fwd<1>, fg, fb, 0, stream, y, x, Yw, Xw, Bo);
  } else {
    hipLaunchKernelGGL(flash_fwd<0>, fg, fb, 0, stream, x, y, (const v4u*)x,
                       (const v4u*)y, A);
    hipLaunchKernelGGL(flash_fwd<0>, fg, fb, 0, stream, y, x, (const v4u*)y,
                       (const v4u*)x, Bo);
  }
}

// Round 9
// 1080.240 us; speedup vs baseline: 1.0064x; 1.0064x over previous
//
#include <hip/hip_runtime.h>
#include <cstdint>
#include <cstddef>

namespace {

constexpr int Bb = 8;
constexpr int Nn = 2048;
constexpr int Dd = 1024;
constexpr int NT = 64;  // kv tiles of 32

typedef _Float16 half8 __attribute__((ext_vector_type(8)));
typedef float f32x4v __attribute__((ext_vector_type(4)));
typedef float f32x16v __attribute__((ext_vector_type(16)));
typedef unsigned int v2u __attribute__((ext_vector_type(2)));
typedef unsigned int v4u __attribute__((ext_vector_type(4)));

__device__ __forceinline__ float fast_exp2(float x) {
  float r;
  asm("v_exp_f32 %0, %1\n\ts_nop 1" : "=v"(r) : "v"(x));
  return r;
}

// pack two f32 -> one u32 of 2x fp16 (RTZ); src0 -> low 16 bits
__device__ __forceinline__ unsigned cvt2(float a, float b) {
  return __builtin_bit_cast(unsigned, __builtin_amdgcn_cvt_pkrtz(a, b));
}

__device__ __forceinline__ void barrier_lgkm() {
  asm volatile("s_waitcnt lgkmcnt(0)" ::: "memory");
  __builtin_amdgcn_s_barrier();
  __builtin_amdgcn_sched_barrier(0);
}

// fp32 -> packed fp16 stream (same element order, 2B/elem)
__global__ void convf16(const float* __restrict__ in, v4u* __restrict__ out) {
  const int n8 = Bb * Nn * Dd / 8;
  int i = blockIdx.x * blockDim.x + threadIdx.x;
  const int stride = gridDim.x * blockDim.x;
  const f32x4v* in4 = (const f32x4v*)in;
  for (; i < n8; i += stride) {
    f32x4v a = in4[2 * i], b = in4[2 * i + 1];
    v4u p;
    p[0] = cvt2(a[0], a[1]);
    p[1] = cvt2(a[2], a[3]);
    p[2] = cvt2(b[0], b[1]);
    p[3] = cvt2(b[2], b[3]);
    out[i] = p;
  }
}

template <int WS>
__device__ __forceinline__ v4u ld8h(const float* f32p, const v4u* h16p) {
  if constexpr (WS) {
    return *h16p;
  } else {
    f32x4v a = *(const f32x4v*)f32p;
    f32x4v b = *(const f32x4v*)(f32p + 4);
    v4u p;
    p[0] = cvt2(a[0], a[1]);
    p[1] = cvt2(a[2], a[3]);
    p[2] = cvt2(b[0], b[1]);
    p[3] = cvt2(b[2], b[3]);
    return p;
  }
}

// Flash attention fwd (no scale), K == V == Y. 512 threads = 8 waves:
// wave = (kvf in 0..1) x (ds in 0..3, 256-d slice). QB=32, KVB=32.
// 2-barrier body:
//  ph1: LOADY(t+1) | PV(t-1) full (kb-split, trr[8] transient) | S(t) | pscr [B1]
//  ph2: softmax(t) (waves 0,1, setprio) || STAGE_WR(t)                     [B2]
template <int WS>
__global__ __launch_bounds__(512, 2) void flash_fwd(
    const float* __restrict__ Qf, const float* __restrict__ Yf,
    const v4u* __restrict__ Qw, const v4u* __restrict__ Yw,
    float* __restrict__ Om) {
  // ybuf tr-window layout:
  // addr(kv,d) = (kv>>2)*8192 + (d>>4)*128 + (kv&3)*32 + (d&15)*2
  __shared__ __attribute__((aligned(128))) char ybuf[65536];
  __shared__ __attribute__((aligned(16))) char pscr[16384];
  __shared__ __attribute__((aligned(16))) char Pb[2048];  // [oct][q] 16B
  __shared__ float sscale[32];
  __shared__ float sinvl[32];
  __shared__ int sflag[2];

  const int tid = (int)threadIdx.x;
  const int w = tid >> 6, l = tid & 63;
  const int lm = l & 15, g = (l >> 4) & 3, g2 = (l >> 5) & 1, l31 = l & 31;
  const int kvf = w >> 2, ds = w & 3;
  const int bid = (int)blockIdx.x, batch = bid & 7, row0 = (bid >> 3) * 32;
  const size_t bY = (size_t)batch * Nn;

  // ---- Q fragments (B-operand): lane(lm,g): q = qh*16+lm,
  // d = ds*256 + ks*32 + g*8 + i   (ks = 0..7)
  v4u qreg[2][8];
#pragma unroll
  for (int qh = 0; qh < 2; ++qh)
#pragma unroll
    for (int ks = 0; ks < 8; ++ks) {
      const int rr = row0 + qh * 16 + lm;
      const int dd_ = ds * 256 + ks * 32 + g * 8;
      qreg[qh][ks] = ld8h<WS>(Qf + (size_t)(bY + rr) * Dd + dd_,
                              Qw + (size_t)(bY + rr) * 128 + (dd_ >> 3));
    }

#define LOADY(dst, t_)                                                        \
  do {                                                                        \
    const int rr_ = (t_)*32 + kvf * 16 + lm;                                  \
    _Pragma("unroll") for (int ks = 0; ks < 8; ++ks) {                        \
      const int dd_ = ds * 256 + ks * 32 + g * 8;                             \
      dst[ks] = ld8h<WS>(Yf + (size_t)(bY + rr_) * Dd + dd_,                  \
                         Yw + (size_t)(bY + rr_) * 128 + (dd_ >> 3));         \
    }                                                                         \
  } while (0)

  // staging write: lane(lm,g) kv=kvf*16+lm, d=ds*256+ks*32+g*8 (16B half-row)
  const unsigned sbase =
      (unsigned)((kvf * 4 + (lm >> 2)) * 8192 + (ds * 16 + (g >> 1)) * 128 +
                 (lm & 3) * 32 + (g & 1) * 16);
#define STAGE_WR(SRC)                                                         \
  do {                                                                        \
    _Pragma("unroll") for (int ks = 0; ks < 8; ++ks)                          \
        *(v4u*)(ybuf + sbase + ks * 256) = SRC[ks];                           \
  } while (0)

  v4u sA[8], sB[8];
  LOADY(sA, 0);

  f32x16v Oacc[4];
#pragma unroll
  for (int i = 0; i < 4; ++i)
#pragma unroll
    for (int j = 0; j < 16; ++j) Oacc[i][j] = 0.0f;

  float m_run = -__builtin_inff();
  float l_run = 0.0f;
  const unsigned ylds = (unsigned)(uintptr_t)&ybuf[0];
  constexpr float L2E = 1.44269504088896f;

  // PV for the previous tile. kb-split keeps only trr[8] live at a time.
  // kb0's tr latency is hidden under the (conditional) rescale.
#define PV_BLOCK()                                                            \
  do {                                                                        \
    half8 pa0 = *(const half8*)(Pb + g2 * 512 + l31 * 16);                    \
    half8 pa1 = *(const half8*)(Pb + (2 + g2) * 512 + l31 * 16);              \
    v2u trr[8];                                                               \
    _Pragma("unroll") for (int df = 0; df < 4; ++df) {                        \
      const unsigned wb =                                                     \
          ylds + (unsigned)((g2 * 2) * 8192 +                                 \
                            ((w * 4 + df) * 2 + (l31 >> 4)) * 128 +           \
                            (l31 & 15) * 8);                                  \
      asm volatile("ds_read_b64_tr_b16 %0, %1"                                \
                   : "=v"(trr[df * 2])                                        \
                   : "v"(wb));                                                \
      asm volatile("ds_read_b64_tr_b16 %0, %1"                                \
                   : "=v"(trr[df * 2 + 1])                                    \
                   : "v"(wb + 8192u));                                        \
    }                                                                         \
    if (sflag[0] | sflag[1]) {                                                \
      _Pragma("unroll") for (int df = 0; df < 4; ++df)                        \
          _Pragma("unroll") for (int r = 0; r < 16; ++r) {                    \
        const int q_ = (r & 3) + 8 * (r >> 2) + 4 * g2;                       \
        Oacc[df][r] *= sscale[q_];                                            \
      }                                                                       \
    }                                                                         \
    asm volatile("s_waitcnt lgkmcnt(0)" ::: "memory");                        \
    __builtin_amdgcn_sched_barrier(0);                                        \
    _Pragma("unroll") for (int df = 0; df < 4; ++df) {                        \
      v4u bu;                                                                 \
      bu[0] = trr[df * 2][0];                                                 \
      bu[1] = trr[df * 2][1];                                                 \
      bu[2] = trr[df * 2 + 1][0];                                             \
      bu[3] = trr[df * 2 + 1][1];                                             \
      Oacc[df] = __builtin_amdgcn_mfma_f32_32x32x16_f16(                      \
          pa0, __builtin_bit_cast(half8, bu), Oacc[df], 0, 0, 0);             \
    }                                                                         \
    _Pragma("unroll") for (int df = 0; df < 4; ++df) {                        \
      const unsigned wb =                                                     \
          ylds + (unsigned)((4 + g2 * 2) * 8192 +                             \
                            ((w * 4 + df) * 2 + (l31 >> 4)) * 128 +           \
                            (l31 & 15) * 8);                                  \
      asm volatile("ds_read_b64_tr_b16 %0, %1"                                \
                   : "=v"(trr[df * 2])                                        \
                   : "v"(wb));                                                \
      asm volatile("ds_read_b64_tr_b16 %0, %1"                                \
                   : "=v"(trr[df * 2 + 1])                                    \
                   : "v"(wb + 8192u));                                        \
    }                                                                         \
    asm volatile("s_waitcnt lgkmcnt(0)" ::: "memory");                        \
    __builtin_amdgcn_sched_barrier(0);                                        \
    _Pragma("unroll") for (int df = 0; df < 4; ++df) {                        \
      v4u bu;                                                                 \
      bu[0] = trr[df * 2][0];                                                 \
      bu[1] = trr[df * 2][1];                                                 \
      bu[2] = trr[df * 2 + 1][0];                                             \
      bu[3] = trr[df * 2 + 1][1];                                             \
      Oacc[df] = __builtin_amdgcn_mfma_f32_32x32x16_f16(                      \
          pa1, __builtin_bit_cast(half8, bu), Oacc[df], 0, 0, 0);             \
    }                                                                         \
  } while (0)

#define TILE_BODY(CUR, NXT, t_, DOPV)                                         \
  do {                                                                        \
    LOADY(NXT, ((t_) + 1) & 63);                                              \
    if (DOPV) PV_BLOCK();                                                     \
    f32x4v acc0 = {0.f, 0.f, 0.f, 0.f}, acc1 = {0.f, 0.f, 0.f, 0.f};          \
    _Pragma("unroll") for (int ks = 0; ks < 8; ++ks) {                        \
      half8 av = __builtin_bit_cast(half8, CUR[ks]);                          \
      acc0 = __builtin_amdgcn_mfma_f32_16x16x32_f16(                          \
          av, __builtin_bit_cast(half8, qreg[0][ks]), acc0, 0, 0, 0);         \
      acc1 = __builtin_amdgcn_mfma_f32_16x16x32_f16(                          \
          av, __builtin_bit_cast(half8, qreg[1][ks]), acc1, 0, 0, 0);         \
    }                                                                         \
    *(f32x4v*)(pscr + (w * 2 + 0) * 1024 + l * 16) = acc0;                    \
    *(f32x4v*)(pscr + (w * 2 + 1) * 1024 + l * 16) = acc1;                    \
    barrier_lgkm(); /* B1: pscr(t) visible; ybuf(t-1) reads done */           \
    if (w < 2) {                                                              \
      __builtin_amdgcn_s_setprio(1);                                          \
      const int qh = w;                                                       \
      f32x4v sa = {0.f, 0.f, 0.f, 0.f}, sb = {0.f, 0.f, 0.f, 0.f};            \
      _Pragma("unroll") for (int s = 0; s < 4; ++s) {                         \
        sa += *(const f32x4v*)(pscr + (s * 2 + qh) * 1024 + l * 16);          \
        sb += *(const f32x4v*)(pscr + ((s + 4) * 2 + qh) * 1024 + l * 16);    \
      }                                                                       \
      float pm = fmaxf(fmaxf(fmaxf(sa[0], sa[1]), fmaxf(sa[2], sa[3])),       \
                       fmaxf(fmaxf(sb[0], sb[1]), fmaxf(sb[2], sb[3])));      \
      pm = fmaxf(pm, __shfl_xor(pm, 16));                                     \
      pm = fmaxf(pm, __shfl_xor(pm, 32));                                     \
      bool defer = (pm <= m_run + 8.0f);                                      \
      bool allw = (bool)__all((int)defer);                                    \
      float scale = 1.0f;                                                     \
      if (!allw) {                                                            \
        float mn = fmaxf(m_run, pm);                                          \
        scale = fast_exp2((m_run - mn) * L2E);                                \
        m_run = mn;                                                           \
      }                                                                       \
      f32x4v ea, eb;                                                          \
      _Pragma("unroll") for (int i = 0; i < 4; ++i) {                         \
        ea[i] = fast_exp2((sa[i] - m_run) * L2E);                             \
        eb[i] = fast_exp2((sb[i] - m_run) * L2E);                             \
      }                                                                       \
      float ps = (ea[0] + ea[1]) + (ea[2] + ea[3]) + (eb[0] + eb[1]) +        \
                 (eb[2] + eb[3]);                                             \
      ps += __shfl_xor(ps, 16);                                               \
      ps += __shfl_xor(ps, 32);                                               \
      l_run = l_run * scale + ps;                                             \
      const int q_ = qh * 16 + lm;                                            \
      v2u pw0, pw1;                                                           \
      pw0[0] = cvt2(ea[0], ea[1]);                                            \
      pw0[1] = cvt2(ea[2], ea[3]);                                            \
      pw1[0] = cvt2(eb[0], eb[1]);                                            \
      pw1[1] = cvt2(eb[2], eb[3]);                                            \
      *(v2u*)(Pb + (g >> 1) * 512 + q_ * 16 + (g & 1) * 8) = pw0;             \
      *(v2u*)(Pb + (2 + (g >> 1)) * 512 + q_ * 16 + (g & 1) * 8) = pw1;       \
      if (l < 16) sscale[q_] = scale;                                         \
      if (l == 0) sflag[qh] = allw ? 0 : 1;                                   \
      __builtin_amdgcn_s_setprio(0);                                          \
    }                                                                         \
    STAGE_WR(CUR);                                                            \
    barrier_lgkm(); /* B2: ybuf(t) + P(t) + stats visible */                  \
  } while (0)

  TILE_BODY(sA, sB, 0, 0);
  TILE_BODY(sB, sA, 1, 1);
  for (int t = 2; t < NT; t += 2) {
    TILE_BODY(sA, sB, t, 1);
    TILE_BODY(sB, sA, t + 1, 1);
  }
  // final tile's PV (t = 63)
  PV_BLOCK();

  // ---- epilogue
  if (w < 2 && l < 16) sinvl[w * 16 + lm] = 1.0f / l_run;
  __syncthreads();
#pragma unroll
  for (int df = 0; df < 4; ++df)
#pragma unroll
    for (int r = 0; r < 16; ++r) {
      const int q_ = (r & 3) + 8 * (r >> 2) + 4 * g2;
      const float inv = sinvl[q_];
      Om[(size_t)(bY + row0 + q_) * Dd + (w * 4 + df) * 32 + l31] =
          Oacc[df][r] * inv;
    }
#undef TILE_BODY
#undef PV_BLOCK
#undef STAGE_WR
#undef LOADY
}

}  // namespace

extern "C" void kernel_launch(void* const* d_in, const int* in_sizes, int n_in,
                              void* d_out, int out_size, void* d_ws,
                              size_t ws_size, hipStream_t stream) {
  (void)in_sizes; (void)n_in; (void)out_size;
  const float* x = (const float*)d_in[0];
  const float* y = (const float*)d_in[1];
  float* A = (float*)d_out;
  float* Bo = A + (size_t)Bb * Nn * Dd;
  const size_t halfws = (size_t)Bb * Nn * Dd * 2;  // 32 MiB per matrix
  dim3 fg(512), fb(512);
  if (d_ws != nullptr && ws_size >= 2 * halfws) {
    v4u* Xw = (v4u*)d_ws;
    v4u* Yw = (v4u*)((char*)d_ws + halfws);
    hipLaunchKernelGGL(convf16, dim3(2048), dim3(256), 0, stream, x, Xw);
    hipLaunchKernelGGL(convf16, dim3(2048), dim3(256), 0, stream, y, Yw);
    hipLaunchKernelGGL(flash_fwd<1>, fg, fb, 0, stream, x, y, Xw, Yw, A);
    hipLaunchKernelGGL(flash_fwd<1>, fg, fb, 0, stream, y, x, Yw, Xw, Bo);
  } else {
    hipLaunchKernelGGL(flash_fwd<0>, fg, fb, 0, stream, x, y, (const v4u*)x,
                       (const v4u*)y, A);
    hipLaunchKernelGGL(flash_fwd<0>, fg, fb, 0, stream, y, x, (const v4u*)y,
                       (const v4u*)x, Bo);
  }
}

// Round 10
// 688.190 us; speedup vs baseline: 1.5798x; 1.5697x over previous
//
#include <hip/hip_runtime.h>
#include <cstdint>
#include <cstddef>

namespace {

constexpr int Bb = 8;
constexpr int Nn = 2048;
constexpr int Dd = 1024;
constexpr int NT = 64;  // kv tiles of 32

typedef _Float16 half8 __attribute__((ext_vector_type(8)));
typedef float f32x4v __attribute__((ext_vector_type(4)));
typedef float f32x16v __attribute__((ext_vector_type(16)));
typedef unsigned int v2u __attribute__((ext_vector_type(2)));
typedef unsigned int v4u __attribute__((ext_vector_type(4)));

__device__ __forceinline__ float fast_exp2(float x) {
  float r;
  asm("v_exp_f32 %0, %1\n\ts_nop 1" : "=v"(r) : "v"(x));
  return r;
}

// pack two f32 -> one u32 of 2x fp16 (RTZ); src0 -> low 16 bits
__device__ __forceinline__ unsigned cvt2(float a, float b) {
  return __builtin_bit_cast(unsigned, __builtin_amdgcn_cvt_pkrtz(a, b));
}

__device__ __forceinline__ void barrier_lgkm() {
  asm volatile("s_waitcnt lgkmcnt(0)" ::: "memory");
  __builtin_amdgcn_s_barrier();
  __builtin_amdgcn_sched_barrier(0);
}

// fp32 -> packed fp16 stream (same element order, 2B/elem)
__global__ void convf16(const float* __restrict__ in, v4u* __restrict__ out) {
  const int n8 = Bb * Nn * Dd / 8;
  int i = blockIdx.x * blockDim.x + threadIdx.x;
  const int stride = gridDim.x * blockDim.x;
  const f32x4v* in4 = (const f32x4v*)in;
  for (; i < n8; i += stride) {
    f32x4v a = in4[2 * i], b = in4[2 * i + 1];
    v4u p;
    p[0] = cvt2(a[0], a[1]);
    p[1] = cvt2(a[2], a[3]);
    p[2] = cvt2(b[0], b[1]);
    p[3] = cvt2(b[2], b[3]);
    out[i] = p;
  }
}

template <int WS>
__device__ __forceinline__ v4u ld8h(const float* f32p, const v4u* h16p) {
  if constexpr (WS) {
    return *h16p;
  } else {
    f32x4v a = *(const f32x4v*)f32p;
    f32x4v b = *(const f32x4v*)(f32p + 4);
    v4u p;
    p[0] = cvt2(a[0], a[1]);
    p[1] = cvt2(a[2], a[3]);
    p[2] = cvt2(b[0], b[1]);
    p[3] = cvt2(b[2], b[3]);
    return p;
  }
}

// Flash attention fwd (no scale), K == V == Y. 512 threads = 8 waves:
// wave = (kvf in 0..1) x (ds in 0..3, 256-d slice). QB=32, KVB=32.
// 2-barrier body, single staging array s[8], LDS ybuf double-buffered:
//  ph1: S(t) from s | LOADY(s, t+1) | pscr wr                        [B1]
//  ph2: w<2: softmax(t)(setprio); all: STAGE_WR(s -> ybuf[(t+1)&1])  [B2]
//  ph3: rescale + PV(t) <- ybuf[t&1], Pb        (no barrier; B1 next iter)
// Hazards: PV(t) rd buf[t&1] vs STAGE(t+2 data) wr buf[t&1] sep by B1(t+1);
// Pb/sscale wr(ph2,t) vs rd(ph3,t) sep by B2; rd(ph3,t) vs wr(ph2,t+1) sep
// by B1(t+1); pscr wr(ph1,t) vs rd(ph2,t) sep by B1; rd(t) vs wr(ph1,t+1)
// sep by B2.
template <int WS>
__global__ __launch_bounds__(512, 2) void flash_fwd(
    const float* __restrict__ Qf, const float* __restrict__ Yf,
    const v4u* __restrict__ Qw, const v4u* __restrict__ Yw,
    float* __restrict__ Om) {
  // ybuf tr-window layout (per buffer):
  // addr(kv,d) = (kv>>2)*8192 + (d>>4)*128 + (kv&3)*32 + (d&15)*2
  __shared__ __attribute__((aligned(128))) char ybuf[2][65536];
  __shared__ __attribute__((aligned(16))) char pscr[16384];
  __shared__ __attribute__((aligned(16))) char Pb[2048];  // [oct][q] 16B
  __shared__ float sscale[32];
  __shared__ float sinvl[32];
  __shared__ int sflag[2];

  const int tid = (int)threadIdx.x;
  const int w = tid >> 6, l = tid & 63;
  const int lm = l & 15, g = (l >> 4) & 3, g2 = (l >> 5) & 1, l31 = l & 31;
  const int kvf = w >> 2, ds = w & 3;
  const int bid = (int)blockIdx.x, batch = bid & 7, row0 = (bid >> 3) * 32;
  const size_t bY = (size_t)batch * Nn;

  // ---- Q fragments (B-operand): lane(lm,g): q = qh*16+lm,
  // d = ds*256 + ks*32 + g*8 + i   (ks = 0..7)
  v4u qreg[2][8];
#pragma unroll
  for (int qh = 0; qh < 2; ++qh)
#pragma unroll
    for (int ks = 0; ks < 8; ++ks) {
      const int rr = row0 + qh * 16 + lm;
      const int dd_ = ds * 256 + ks * 32 + g * 8;
      qreg[qh][ks] = ld8h<WS>(Qf + (size_t)(bY + rr) * Dd + dd_,
                              Qw + (size_t)(bY + rr) * 128 + (dd_ >> 3));
    }

#define LOADY(dst, t_)                                                        \
  do {                                                                        \
    const int rr_ = (t_)*32 + kvf * 16 + lm;                                  \
    _Pragma("unroll") for (int ks = 0; ks < 8; ++ks) {                        \
      const int dd_ = ds * 256 + ks * 32 + g * 8;                             \
      dst[ks] = ld8h<WS>(Yf + (size_t)(bY + rr_) * Dd + dd_,                  \
                         Yw + (size_t)(bY + rr_) * 128 + (dd_ >> 3));         \
    }                                                                         \
  } while (0)

  // staging write: lane(lm,g) kv=kvf*16+lm, d=ds*256+ks*32+g*8 (16B half-row)
  const unsigned sbase =
      (unsigned)((kvf * 4 + (lm >> 2)) * 8192 + (ds * 16 + (g >> 1)) * 128 +
                 (lm & 3) * 32 + (g & 1) * 16);
#define STAGE_WR(SRC, BASE)                                                   \
  do {                                                                        \
    _Pragma("unroll") for (int ks = 0; ks < 8; ++ks)                          \
        *(v4u*)((BASE) + sbase + ks * 256) = SRC[ks];                         \
  } while (0)

  v4u s[8];
  LOADY(s, 0);
  STAGE_WR(s, &ybuf[0][0]);

  f32x16v Oacc[4];
#pragma unroll
  for (int i = 0; i < 4; ++i)
#pragma unroll
    for (int j = 0; j < 16; ++j) Oacc[i][j] = 0.0f;

  float m_run = -__builtin_inff();
  float l_run = 0.0f;
  const unsigned ylds0 = (unsigned)(uintptr_t)&ybuf[0][0];
  const unsigned ylds1 = ylds0 + 65536u;
  constexpr float L2E = 1.44269504088896f;

  __syncthreads();

  // PV(t): rescale + P(b128 contig) + kb-split tr reads (trr[8] transient).
#define PV_BLOCK(YPV)                                                         \
  do {                                                                        \
    half8 pa0 = *(const half8*)(Pb + g2 * 512 + l31 * 16);                    \
    half8 pa1 = *(const half8*)(Pb + (2 + g2) * 512 + l31 * 16);              \
    v2u trr[8];                                                               \
    _Pragma("unroll") for (int df = 0; df < 4; ++df) {                        \
      const unsigned wb =                                                     \
          (YPV) + (unsigned)((g2 * 2) * 8192 +                                \
                             ((w * 4 + df) * 2 + (l31 >> 4)) * 128 +          \
                             (l31 & 15) * 8);                                 \
      asm volatile("ds_read_b64_tr_b16 %0, %1"                                \
                   : "=v"(trr[df * 2])                                        \
                   : "v"(wb));                                                \
      asm volatile("ds_read_b64_tr_b16 %0, %1"                                \
                   : "=v"(trr[df * 2 + 1])                                    \
                   : "v"(wb + 8192u));                                        \
    }                                                                         \
    if (sflag[0] | sflag[1]) {                                                \
      _Pragma("unroll") for (int df = 0; df < 4; ++df)                        \
          _Pragma("unroll") for (int r = 0; r < 16; ++r) {                    \
        const int q_ = (r & 3) + 8 * (r >> 2) + 4 * g2;                       \
        Oacc[df][r] *= sscale[q_];                                            \
      }                                                                       \
    }                                                                         \
    asm volatile("s_waitcnt lgkmcnt(0)" ::: "memory");                        \
    __builtin_amdgcn_sched_barrier(0);                                        \
    _Pragma("unroll") for (int df = 0; df < 4; ++df) {                        \
      v4u bu;                                                                 \
      bu[0] = trr[df * 2][0];                                                 \
      bu[1] = trr[df * 2][1];                                                 \
      bu[2] = trr[df * 2 + 1][0];                                             \
      bu[3] = trr[df * 2 + 1][1];                                             \
      Oacc[df] = __builtin_amdgcn_mfma_f32_32x32x16_f16(                      \
          pa0, __builtin_bit_cast(half8, bu), Oacc[df], 0, 0, 0);             \
    }                                                                         \
    _Pragma("unroll") for (int df = 0; df < 4; ++df) {                        \
      const unsigned wb =                                                     \
          (YPV) + (unsigned)((4 + g2 * 2) * 8192 +                            \
                             ((w * 4 + df) * 2 + (l31 >> 4)) * 128 +          \
                             (l31 & 15) * 8);                                 \
      asm volatile("ds_read_b64_tr_b16 %0, %1"                                \
                   : "=v"(trr[df * 2])                                        \
                   : "v"(wb));                                                \
      asm volatile("ds_read_b64_tr_b16 %0, %1"                                \
                   : "=v"(trr[df * 2 + 1])                                    \
                   : "v"(wb + 8192u));                                        \
    }                                                                         \
    asm volatile("s_waitcnt lgkmcnt(0)" ::: "memory");                        \
    __builtin_amdgcn_sched_barrier(0);                                        \
    _Pragma("unroll") for (int df = 0; df < 4; ++df) {                        \
      v4u bu;                                                                 \
      bu[0] = trr[df * 2][0];                                                 \
      bu[1] = trr[df * 2][1];                                                 \
      bu[2] = trr[df * 2 + 1][0];                                             \
      bu[3] = trr[df * 2 + 1][1];                                             \
      Oacc[df] = __builtin_amdgcn_mfma_f32_32x32x16_f16(                      \
          pa1, __builtin_bit_cast(half8, bu), Oacc[df], 0, 0, 0);             \
    }                                                                         \
  } while (0)

#define TILE_BODY(t_, YPV, YST)                                               \
  do {                                                                        \
    f32x4v acc0 = {0.f, 0.f, 0.f, 0.f}, acc1 = {0.f, 0.f, 0.f, 0.f};          \
    _Pragma("unroll") for (int ks = 0; ks < 8; ++ks) {                        \
      half8 av = __builtin_bit_cast(half8, s[ks]);                            \
      acc0 = __builtin_amdgcn_mfma_f32_16x16x32_f16(                          \
          av, __builtin_bit_cast(half8, qreg[0][ks]), acc0, 0, 0, 0);         \
      acc1 = __builtin_amdgcn_mfma_f32_16x16x32_f16(                          \
          av, __builtin_bit_cast(half8, qreg[1][ks]), acc1, 0, 0, 0);         \
    }                                                                         \
    LOADY(s, ((t_) + 1) & 63);                                                \
    *(f32x4v*)(pscr + (w * 2 + 0) * 1024 + l * 16) = acc0;                    \
    *(f32x4v*)(pscr + (w * 2 + 1) * 1024 + l * 16) = acc1;                    \
    barrier_lgkm(); /* B1 */                                                  \
    if (w < 2) {                                                              \
      __builtin_amdgcn_s_setprio(1);                                          \
      const int qh = w;                                                       \
      f32x4v sa = {0.f, 0.f, 0.f, 0.f}, sb = {0.f, 0.f, 0.f, 0.f};            \
      _Pragma("unroll") for (int s_ = 0; s_ < 4; ++s_) {                      \
        sa += *(const f32x4v*)(pscr + (s_ * 2 + qh) * 1024 + l * 16);         \
        sb += *(const f32x4v*)(pscr + ((s_ + 4) * 2 + qh) * 1024 + l * 16);   \
      }                                                                       \
      float pm = fmaxf(fmaxf(fmaxf(sa[0], sa[1]), fmaxf(sa[2], sa[3])),       \
                       fmaxf(fmaxf(sb[0], sb[1]), fmaxf(sb[2], sb[3])));      \
      pm = fmaxf(pm, __shfl_xor(pm, 16));                                     \
      pm = fmaxf(pm, __shfl_xor(pm, 32));                                     \
      bool defer = (pm <= m_run + 8.0f);                                      \
      bool allw = (bool)__all((int)defer);                                    \
      float scale = 1.0f;                                                     \
      if (!allw) {                                                            \
        float mn = fmaxf(m_run, pm);                                          \
        scale = fast_exp2((m_run - mn) * L2E);                                \
        m_run = mn;                                                           \
      }                                                                       \
      f32x4v ea, eb;                                                          \
      _Pragma("unroll") for (int i = 0; i < 4; ++i) {                         \
        ea[i] = fast_exp2((sa[i] - m_run) * L2E);                             \
        eb[i] = fast_exp2((sb[i] - m_run) * L2E);                             \
      }                                                                       \
      float ps = (ea[0] + ea[1]) + (ea[2] + ea[3]) + (eb[0] + eb[1]) +        \
                 (eb[2] + eb[3]);                                             \
      ps += __shfl_xor(ps, 16);                                               \
      ps += __shfl_xor(ps, 32);                                               \
      l_run = l_run * scale + ps;                                             \
      const int q_ = qh * 16 + lm;                                            \
      v2u pw0, pw1;                                                           \
      pw0[0] = cvt2(ea[0], ea[1]);                                            \
      pw0[1] = cvt2(ea[2], ea[3]);                                            \
      pw1[0] = cvt2(eb[0], eb[1]);                                            \
      pw1[1] = cvt2(eb[2], eb[3]);                                            \
      *(v2u*)(Pb + (g >> 1) * 512 + q_ * 16 + (g & 1) * 8) = pw0;             \
      *(v2u*)(Pb + (2 + (g >> 1)) * 512 + q_ * 16 + (g & 1) * 8) = pw1;       \
      if (l < 16) sscale[q_] = scale;                                         \
      if (l == 0) sflag[qh] = allw ? 0 : 1;                                   \
      __builtin_amdgcn_s_setprio(0);                                          \
    }                                                                         \
    STAGE_WR(s, YST);                                                         \
    barrier_lgkm(); /* B2 */                                                  \
    PV_BLOCK(YPV);                                                            \
  } while (0)

  for (int t = 0; t < NT; t += 2) {
    TILE_BODY(t, ylds0, &ybuf[1][0]);
    TILE_BODY(t + 1, ylds1, &ybuf[0][0]);
  }

  // ---- epilogue
  if (w < 2 && l < 16) sinvl[w * 16 + lm] = 1.0f / l_run;
  __syncthreads();
#pragma unroll
  for (int df = 0; df < 4; ++df)
#pragma unroll
    for (int r = 0; r < 16; ++r) {
      const int q_ = (r & 3) + 8 * (r >> 2) + 4 * g2;
      const float inv = sinvl[q_];
      Om[(size_t)(bY + row0 + q_) * Dd + (w * 4 + df) * 32 + l31] =
          Oacc[df][r] * inv;
    }
#undef TILE_BODY
#undef PV_BLOCK
#undef STAGE_WR
#undef LOADY
}

}  // namespace

extern "C" void kernel_launch(void* const* d_in, const int* in_sizes, int n_in,
                              void* d_out, int out_size, void* d_ws,
                              size_t ws_size, hipStream_t stream) {
  (void)in_sizes; (void)n_in; (void)out_size;
  const float* x = (const float*)d_in[0];
  const float* y = (const float*)d_in[1];
  float* A = (float*)d_out;
  float* Bo = A + (size_t)Bb * Nn * Dd;
  const size_t halfws = (size_t)Bb * Nn * Dd * 2;  // 32 MiB per matrix
  dim3 fg(512), fb(512);
  if (d_ws != nullptr && ws_size >= 2 * halfws) {
    v4u* Xw = (v4u*)d_ws;
    v4u* Yw = (v4u*)((char*)d_ws + halfws);
    hipLaunchKernelGGL(convf16, dim3(2048), dim3(256), 0, stream, x, Xw);
    hipLaunchKernelGGL(convf16, dim3(2048), dim3(256), 0, stream, y, Yw);
    hipLaunchKernelGGL(flash_fwd<1>, fg, fb, 0, stream, x, y, Xw, Yw, A);
    hipLaunchKernelGGL(flash_fwd<1>, fg, fb, 0, stream, y, x, Yw, Xw, Bo);
  } else {
    hipLaunchKernelGGL(flash_fwd<0>, fg, fb, 0, stream, x, y, (const v4u*)x,
                       (const v4u*)y, A);
    hipLaunchKernelGGL(flash_fwd<0>, fg, fb, 0, stream, y, x, (const v4u*)y,
                       (const v4u*)x, Bo);
  }
}

// Round 11
// 572.825 us; speedup vs baseline: 1.8979x; 1.2014x over previous
//
#include <hip/hip_runtime.h>
#include <cstdint>
#include <cstddef>

namespace {

constexpr int Bb = 8;
constexpr int Nn = 2048;
constexpr int Dd = 1024;
constexpr int NT = 64;  // kv tiles of 32

typedef _Float16 half8 __attribute__((ext_vector_type(8)));
typedef float f32x4v __attribute__((ext_vector_type(4)));
typedef float f32x16v __attribute__((ext_vector_type(16)));
typedef unsigned int v2u __attribute__((ext_vector_type(2)));
typedef unsigned int v4u __attribute__((ext_vector_type(4)));

__device__ __forceinline__ float fast_exp2(float x) {
  float r;
  asm("v_exp_f32 %0, %1\n\ts_nop 1" : "=v"(r) : "v"(x));
  return r;
}

// pack two f32 -> one u32 of 2x fp16 (RTZ); src0 -> low 16 bits
__device__ __forceinline__ unsigned cvt2(float a, float b) {
  return __builtin_bit_cast(unsigned, __builtin_amdgcn_cvt_pkrtz(a, b));
}

// quad-lane (stride-1/2) butterfly reductions via DPP quad_perm (VALU pipe,
// replaces ds_bpermute-based __shfl_xor). 0xB1 = [1,0,3,2], 0x4E = [2,3,0,1].
__device__ __forceinline__ float quad_max(float v) {
  int a = __builtin_amdgcn_update_dpp(0, __builtin_bit_cast(int, v), 0xB1,
                                      0xF, 0xF, true);
  float m = fmaxf(v, __builtin_bit_cast(float, a));
  int b = __builtin_amdgcn_update_dpp(0, __builtin_bit_cast(int, m), 0x4E,
                                      0xF, 0xF, true);
  return fmaxf(m, __builtin_bit_cast(float, b));
}
__device__ __forceinline__ float quad_add(float v) {
  int a = __builtin_amdgcn_update_dpp(0, __builtin_bit_cast(int, v), 0xB1,
                                      0xF, 0xF, true);
  float s = v + __builtin_bit_cast(float, a);
  int b = __builtin_amdgcn_update_dpp(0, __builtin_bit_cast(int, s), 0x4E,
                                      0xF, 0xF, true);
  return s + __builtin_bit_cast(float, b);
}

__device__ __forceinline__ void barrier_lgkm() {
  asm volatile("s_waitcnt lgkmcnt(0)" ::: "memory");
  __builtin_amdgcn_s_barrier();
  __builtin_amdgcn_sched_barrier(0);
}
__device__ __forceinline__ void barrier_plain() {
  __builtin_amdgcn_s_barrier();
  __builtin_amdgcn_sched_barrier(0);
}

// fp32 -> packed fp16 stream (same element order, 2B/elem)
__global__ void convf16(const float* __restrict__ in, v4u* __restrict__ out) {
  const int n8 = Bb * Nn * Dd / 8;
  int i = blockIdx.x * blockDim.x + threadIdx.x;
  const int stride = gridDim.x * blockDim.x;
  const f32x4v* in4 = (const f32x4v*)in;
  for (; i < n8; i += stride) {
    f32x4v a = in4[2 * i], b = in4[2 * i + 1];
    v4u p;
    p[0] = cvt2(a[0], a[1]);
    p[1] = cvt2(a[2], a[3]);
    p[2] = cvt2(b[0], b[1]);
    p[3] = cvt2(b[2], b[3]);
    out[i] = p;
  }
}

template <int WS>
__device__ __forceinline__ v4u ld8h(const float* f32p, const v4u* h16p) {
  if constexpr (WS) {
    return *h16p;
  } else {
    f32x4v a = *(const f32x4v*)f32p;
    f32x4v b = *(const f32x4v*)(f32p + 4);
    v4u p;
    p[0] = cvt2(a[0], a[1]);
    p[1] = cvt2(a[2], a[3]);
    p[2] = cvt2(b[0], b[1]);
    p[3] = cvt2(b[2], b[3]);
    return p;
  }
}

// Flash attention fwd (no scale), K == V == Y. 512 threads = 8 waves:
// wave = (kvf in 0..1) x (ds in 0..3, 256-d slice). QB=32, KVB=32.
// R6 schedule (3 barriers/tile) + transposed pscr2 + quad-DPP softmax.
template <int WS>
__global__ __launch_bounds__(512, 2) void flash_fwd(
    const float* __restrict__ Qf, const float* __restrict__ Yf,
    const v4u* __restrict__ Qw, const v4u* __restrict__ Yw,
    float* __restrict__ Om) {
  // ybuf tr-window layout:
  // addr(kv,d) = (kv>>2)*8192 + (d>>4)*128 + (kv&3)*32 + (d&15)*2
  __shared__ __attribute__((aligned(128))) char ybuf[65536];
  // pscr2[ds][q][kv] f32, kv-row padded 32->36 (144B, 16B-aligned rows)
  __shared__ __attribute__((aligned(16))) float pscr2[4][32][36];
  __shared__ __attribute__((aligned(16))) char Pb[2048];  // [oct][q] 16B
  __shared__ float sscale[32];
  __shared__ float sinvl[32];
  __shared__ int sflag[2];

  const int tid = (int)threadIdx.x;
  const int w = tid >> 6, l = tid & 63;
  const int lm = l & 15, g = (l >> 4) & 3, g2 = (l >> 5) & 1, l31 = l & 31;
  const int kvf = w >> 2, ds = w & 3;
  const int bid = (int)blockIdx.x, batch = bid & 7, row0 = (bid >> 3) * 32;
  const size_t bY = (size_t)batch * Nn;

  // ---- Q fragments (B-operand): lane(lm,g): q = qh*16+lm,
  // d = ds*256 + ks*32 + g*8 + i   (ks = 0..7)
  v4u qreg[2][8];
#pragma unroll
  for (int qh = 0; qh < 2; ++qh)
#pragma unroll
    for (int ks = 0; ks < 8; ++ks) {
      const int rr = row0 + qh * 16 + lm;
      const int dd_ = ds * 256 + ks * 32 + g * 8;
      qreg[qh][ks] = ld8h<WS>(Qf + (size_t)(bY + rr) * Dd + dd_,
                              Qw + (size_t)(bY + rr) * 128 + (dd_ >> 3));
    }

#define LOADY(dst, t_)                                                        \
  do {                                                                        \
    const int rr_ = (t_)*32 + kvf * 16 + lm;                                  \
    _Pragma("unroll") for (int ks = 0; ks < 8; ++ks) {                        \
      const int dd_ = ds * 256 + ks * 32 + g * 8;                             \
      dst[ks] = ld8h<WS>(Yf + (size_t)(bY + rr_) * Dd + dd_,                  \
                         Yw + (size_t)(bY + rr_) * 128 + (dd_ >> 3));         \
    }                                                                         \
  } while (0)

  // staging write: lane(lm,g) kv=kvf*16+lm, d=ds*256+ks*32+g*8 (16B half-row)
  const unsigned sbase =
      (unsigned)((kvf * 4 + (lm >> 2)) * 8192 + (ds * 16 + (g >> 1)) * 128 +
                 (lm & 3) * 32 + (g & 1) * 16);
#define STAGE_WR(SRC)                                                         \
  do {                                                                        \
    _Pragma("unroll") for (int ks = 0; ks < 8; ++ks)                          \
        *(v4u*)(ybuf + sbase + ks * 256) = SRC[ks];                           \
  } while (0)

  v4u sA[8], sB[8];
  LOADY(sA, 0);
  STAGE_WR(sA);

  f32x16v Oacc[4];
#pragma unroll
  for (int i = 0; i < 4; ++i)
#pragma unroll
    for (int j = 0; j < 16; ++j) Oacc[i][j] = 0.0f;

  float m_run = -__builtin_inff();
  float l_run = 0.0f;
  const unsigned ylds = (unsigned)(uintptr_t)&ybuf[0];
  constexpr float L2E = 1.44269504088896f;

  __syncthreads();

#define TILE_BODY(CUR, NXT, t_)                                               \
  do {                                                                        \
    f32x4v acc0 = {0.f, 0.f, 0.f, 0.f}, acc1 = {0.f, 0.f, 0.f, 0.f};          \
    _Pragma("unroll") for (int ks = 0; ks < 8; ++ks) {                        \
      half8 av = __builtin_bit_cast(half8, CUR[ks]);                          \
      acc0 = __builtin_amdgcn_mfma_f32_16x16x32_f16(                          \
          av, __builtin_bit_cast(half8, qreg[0][ks]), acc0, 0, 0, 0);         \
      acc1 = __builtin_amdgcn_mfma_f32_16x16x32_f16(                          \
          av, __builtin_bit_cast(half8, qreg[1][ks]), acc1, 0, 0, 0);         \
    }                                                                         \
    LOADY(NXT, ((t_) + 1) & 63);                                              \
    /* transposed partial store: [ds][q][kv], kv = kvf*16+g*4+r */            \
    *(f32x4v*)&pscr2[ds][lm][kvf * 16 + g * 4] = acc0;                        \
    *(f32x4v*)&pscr2[ds][16 + lm][kvf * 16 + g * 4] = acc1;                   \
    barrier_lgkm(); /* B1: partials visible */                                \
    if (w < 2) {                                                              \
      __builtin_amdgcn_s_setprio(1);                                          \
      const int rq = w * 16 + (l >> 2); /* global q row */                    \
      const int c = l & 3;              /* kv octet */                        \
      f32x4v lo = {0.f, 0.f, 0.f, 0.f}, hi = {0.f, 0.f, 0.f, 0.f};            \
      _Pragma("unroll") for (int s_ = 0; s_ < 4; ++s_) {                      \
        lo += *(const f32x4v*)&pscr2[s_][rq][c * 8];                          \
        hi += *(const f32x4v*)&pscr2[s_][rq][c * 8 + 4];                      \
      }                                                                       \
      float pm = fmaxf(fmaxf(fmaxf(lo[0], lo[1]), fmaxf(lo[2], lo[3])),       \
                       fmaxf(fmaxf(hi[0], hi[1]), fmaxf(hi[2], hi[3])));      \
      pm = quad_max(pm);                                                      \
      bool defer = (pm <= m_run + 8.0f);                                      \
      bool allw = (bool)__all((int)defer);                                    \
      float scale = 1.0f;                                                     \
      if (!allw) {                                                            \
        float mn = fmaxf(m_run, pm);                                          \
        scale = fast_exp2((m_run - mn) * L2E);                                \
        m_run = mn;                                                           \
      }                                                                       \
      f32x4v ea, eb;                                                          \
      _Pragma("unroll") for (int i = 0; i < 4; ++i) {                         \
        ea[i] = fast_exp2((lo[i] - m_run) * L2E);                             \
        eb[i] = fast_exp2((hi[i] - m_run) * L2E);                             \
      }                                                                       \
      float ps = (ea[0] + ea[1]) + (ea[2] + ea[3]) + (eb[0] + eb[1]) +        \
                 (eb[2] + eb[3]);                                             \
      ps = quad_add(ps);                                                      \
      l_run = l_run * scale + ps;                                             \
      v4u pk;                                                                 \
      pk[0] = cvt2(ea[0], ea[1]);                                             \
      pk[1] = cvt2(ea[2], ea[3]);                                             \
      pk[2] = cvt2(eb[0], eb[1]);                                             \
      pk[3] = cvt2(eb[2], eb[3]);                                             \
      *(v4u*)(Pb + c * 512 + rq * 16) = pk; /* oct c, q rq, kv c*8..+8 */     \
      if (c == 0) sscale[rq] = scale;                                         \
      if (l == 0) sflag[w] = allw ? 0 : 1;                                    \
      __builtin_amdgcn_s_setprio(0);                                          \
    }                                                                         \
    barrier_lgkm(); /* B2: P + stats visible */                               \
    if (sflag[0] | sflag[1]) {                                                \
      _Pragma("unroll") for (int df = 0; df < 4; ++df)                        \
          _Pragma("unroll") for (int r = 0; r < 16; ++r) {                    \
        const int q_ = (r & 3) + 8 * (r >> 2) + 4 * g2;                       \
        Oacc[df][r] *= sscale[q_];                                            \
      }                                                                       \
    }                                                                         \
    _Pragma("unroll") for (int kb = 0; kb < 2; ++kb) {                        \
      half8 pa = *(const half8*)(Pb + (kb * 2 + g2) * 512 + l31 * 16);        \
      v2u trr[8];                                                             \
      _Pragma("unroll") for (int df = 0; df < 4; ++df) {                      \
        const unsigned wb =                                                   \
            ylds + (unsigned)((kb * 4 + g2 * 2) * 8192 +                      \
                              ((w * 4 + df) * 2 + (l31 >> 4)) * 128 +         \
                              (l31 & 15) * 8);                                \
        asm volatile("ds_read_b64_tr_b16 %0, %1"                              \
                     : "=v"(trr[df * 2])                                      \
                     : "v"(wb));                                              \
        asm volatile("ds_read_b64_tr_b16 %0, %1"                              \
                     : "=v"(trr[df * 2 + 1])                                  \
                     : "v"(wb + 8192u));                                      \
      }                                                                       \
    asm volatile("s_waitcnt lgkmcnt(0)" ::: "memory");                        \
    __builtin_amdgcn_sched_barrier(0);                                        \
      _Pragma("unroll") for (int df = 0; df < 4; ++df) {                      \
        v4u bu;                                                               \
        bu[0] = trr[df * 2][0];                                               \
        bu[1] = trr[df * 2][1];                                               \
        bu[2] = trr[df * 2 + 1][0];                                           \
        bu[3] = trr[df * 2 + 1][1];                                           \
        Oacc[df] = __builtin_amdgcn_mfma_f32_32x32x16_f16(                    \
            pa, __builtin_bit_cast(half8, bu), Oacc[df], 0, 0, 0);            \
      }                                                                       \
    }                                                                         \
    barrier_plain(); /* B3: PV reads done, ybuf free */                       \
    STAGE_WR(NXT);                                                            \
  } while (0)

  for (int t = 0; t < NT; t += 2) {
    TILE_BODY(sA, sB, t);
    TILE_BODY(sB, sA, t + 1);
  }

  // ---- epilogue
  if (w < 2 && (l & 3) == 0) sinvl[w * 16 + (l >> 2)] = 1.0f / l_run;
  __syncthreads();
#pragma unroll
  for (int df = 0; df < 4; ++df)
#pragma unroll
    for (int r = 0; r < 16; ++r) {
      const int q_ = (r & 3) + 8 * (r >> 2) + 4 * g2;
      const float inv = sinvl[q_];
      Om[(size_t)(bY + row0 + q_) * Dd + (w * 4 + df) * 32 + l31] =
          Oacc[df][r] * inv;
    }
#undef TILE_BODY
#undef STAGE_WR
#undef LOADY
}

}  // namespace

extern "C" void kernel_launch(void* const* d_in, const int* in_sizes, int n_in,
                              void* d_out, int out_size, void* d_ws,
                              size_t ws_size, hipStream_t stream) {
  (void)in_sizes; (void)n_in; (void)out_size;
  const float* x = (const float*)d_in[0];
  const float* y = (const float*)d_in[1];
  float* A = (float*)d_out;
  float* Bo = A + (size_t)Bb * Nn * Dd;
  const size_t halfws = (size_t)Bb * Nn * Dd * 2;  // 32 MiB per matrix
  dim3 fg(512), fb(512);
  if (d_ws != nullptr && ws_size >= 2 * halfws) {
    v4u* Xw = (v4u*)d_ws;
    v4u* Yw = (v4u*)((char*)d_ws + halfws);
    hipLaunchKernelGGL(convf16, dim3(2048), dim3(256), 0, stream, x, Xw);
    hipLaunchKernelGGL(convf16, dim3(2048), dim3(256), 0, stream, y, Yw);
    hipLaunchKernelGGL(flash_fwd<1>, fg, fb, 0, stream, x, y, Xw, Yw, A);
    hipLaunchKernelGGL(flash_fwd<1>, fg, fb, 0, stream, y, x, Yw, Xw, Bo);
  } else {
    hipLaunchKernelGGL(flash_fwd<0>, fg, fb, 0, stream, x, y, (const v4u*)x,
                       (const v4u*)y, A);
    hipLaunchKernelGGL(flash_fwd<0>, fg, fb, 0, stream, y, x, (const v4u*)y,
                       (const v4u*)x, Bo);
  }
}

// Round 12
// 542.440 us; speedup vs baseline: 2.0042x; 1.0560x over previous
//
#include <hip/hip_runtime.h>
#include <cstdint>
#include <cstddef>

namespace {

constexpr int Bb = 8;
constexpr int Nn = 2048;
constexpr int Dd = 1024;
constexpr int NT = 64;  // kv tiles of 32

typedef _Float16 half8 __attribute__((ext_vector_type(8)));
typedef float f32x4v __attribute__((ext_vector_type(4)));
typedef float f32x16v __attribute__((ext_vector_type(16)));
typedef unsigned int v2u __attribute__((ext_vector_type(2)));
typedef unsigned int v4u __attribute__((ext_vector_type(4)));

__device__ __forceinline__ float fast_exp2(float x) {
  float r;
  asm("v_exp_f32 %0, %1\n\ts_nop 1" : "=v"(r) : "v"(x));
  return r;
}

// pack two f32 -> one u32 of 2x fp16 (RTZ); src0 -> low 16 bits
__device__ __forceinline__ unsigned cvt2(float a, float b) {
  return __builtin_bit_cast(unsigned, __builtin_amdgcn_cvt_pkrtz(a, b));
}

// quad-lane butterfly reductions via DPP quad_perm (VALU pipe).
__device__ __forceinline__ float quad_max(float v) {
  int a = __builtin_amdgcn_update_dpp(0, __builtin_bit_cast(int, v), 0xB1,
                                      0xF, 0xF, true);
  float m = fmaxf(v, __builtin_bit_cast(float, a));
  int b = __builtin_amdgcn_update_dpp(0, __builtin_bit_cast(int, m), 0x4E,
                                      0xF, 0xF, true);
  return fmaxf(m, __builtin_bit_cast(float, b));
}
__device__ __forceinline__ float quad_add(float v) {
  int a = __builtin_amdgcn_update_dpp(0, __builtin_bit_cast(int, v), 0xB1,
                                      0xF, 0xF, true);
  float s = v + __builtin_bit_cast(float, a);
  int b = __builtin_amdgcn_update_dpp(0, __builtin_bit_cast(int, s), 0x4E,
                                      0xF, 0xF, true);
  return s + __builtin_bit_cast(float, b);
}

__device__ __forceinline__ void barrier_lgkm() {
  asm volatile("s_waitcnt lgkmcnt(0)" ::: "memory");
  __builtin_amdgcn_s_barrier();
  __builtin_amdgcn_sched_barrier(0);
}
__device__ __forceinline__ void barrier_plain() {
  __builtin_amdgcn_s_barrier();
  __builtin_amdgcn_sched_barrier(0);
}

// fp32 -> packed fp16 stream (same element order, 2B/elem)
__global__ void convf16(const float* __restrict__ in, v4u* __restrict__ out) {
  const int n8 = Bb * Nn * Dd / 8;
  int i = blockIdx.x * blockDim.x + threadIdx.x;
  const int stride = gridDim.x * blockDim.x;
  const f32x4v* in4 = (const f32x4v*)in;
  for (; i < n8; i += stride) {
    f32x4v a = in4[2 * i], b = in4[2 * i + 1];
    v4u p;
    p[0] = cvt2(a[0], a[1]);
    p[1] = cvt2(a[2], a[3]);
    p[2] = cvt2(b[0], b[1]);
    p[3] = cvt2(b[2], b[3]);
    out[i] = p;
  }
}

template <int WS>
__device__ __forceinline__ v4u ld8h(const float* f32p, const v4u* h16p) {
  if constexpr (WS) {
    return *h16p;
  } else {
    f32x4v a = *(const f32x4v*)f32p;
    f32x4v b = *(const f32x4v*)(f32p + 4);
    v4u p;
    p[0] = cvt2(a[0], a[1]);
    p[1] = cvt2(a[2], a[3]);
    p[2] = cvt2(b[0], b[1]);
    p[3] = cvt2(b[2], b[3]);
    return p;
  }
}

// Flash attention fwd (no scale), K == V == Y. 512 threads = 8 waves:
// wave = (kvf in 0..1) x (ds in 0..3, 256-d slice). QB=32, KVB=32.
// R10 schedule with tr-reads hoisted to overlap softmax, single s[8]:
//  ph A: S(t) | LOADY(s,t+1) | pscr2 wr                       [B1]
//  ph B: w>=2: issue 16 tr reads; w<2: softmax(t) then issue  [B2 drains]
//  ph C: Pb reads + rescale + 16 PV MFMAs                     [B3]
//  ph D: STAGE_WR(s -> ybuf)
template <int WS>
__global__ __launch_bounds__(512, 2) void flash_fwd(
    const float* __restrict__ Qf, const float* __restrict__ Yf,
    const v4u* __restrict__ Qw, const v4u* __restrict__ Yw,
    float* __restrict__ Om) {
  // ybuf tr-window layout:
  // addr(kv,d) = (kv>>2)*8192 + (d>>4)*128 + (kv&3)*32 + (d&15)*2
  __shared__ __attribute__((aligned(128))) char ybuf[65536];
  // pscr2[ds][q][kv] f32, kv-row padded 32->36
  __shared__ __attribute__((aligned(16))) float pscr2[4][32][36];
  __shared__ __attribute__((aligned(16))) char Pb[2048];  // [oct][q] 16B
  __shared__ float sscale[32];
  __shared__ float sinvl[32];
  __shared__ int sflag[2];

  const int tid = (int)threadIdx.x;
  const int w = tid >> 6, l = tid & 63;
  const int lm = l & 15, g = (l >> 4) & 3, g2 = (l >> 5) & 1, l31 = l & 31;
  const int kvf = w >> 2, ds = w & 3;
  const int bid = (int)blockIdx.x, batch = bid & 7, row0 = (bid >> 3) * 32;
  const size_t bY = (size_t)batch * Nn;

  // ---- Q fragments (B-operand): lane(lm,g): q = qh*16+lm,
  // d = ds*256 + ks*32 + g*8 + i   (ks = 0..7)
  v4u qreg[2][8];
#pragma unroll
  for (int qh = 0; qh < 2; ++qh)
#pragma unroll
    for (int ks = 0; ks < 8; ++ks) {
      const int rr = row0 + qh * 16 + lm;
      const int dd_ = ds * 256 + ks * 32 + g * 8;
      qreg[qh][ks] = ld8h<WS>(Qf + (size_t)(bY + rr) * Dd + dd_,
                              Qw + (size_t)(bY + rr) * 128 + (dd_ >> 3));
    }

#define LOADY(dst, t_)                                                        \
  do {                                                                        \
    const int rr_ = (t_)*32 + kvf * 16 + lm;                                  \
    _Pragma("unroll") for (int ks = 0; ks < 8; ++ks) {                        \
      const int dd_ = ds * 256 + ks * 32 + g * 8;                             \
      dst[ks] = ld8h<WS>(Yf + (size_t)(bY + rr_) * Dd + dd_,                  \
                         Yw + (size_t)(bY + rr_) * 128 + (dd_ >> 3));         \
    }                                                                         \
  } while (0)

  // staging write: lane(lm,g) kv=kvf*16+lm, d=ds*256+ks*32+g*8 (16B half-row)
  const unsigned sbase =
      (unsigned)((kvf * 4 + (lm >> 2)) * 8192 + (ds * 16 + (g >> 1)) * 128 +
                 (lm & 3) * 32 + (g & 1) * 16);
#define STAGE_WR(SRC)                                                         \
  do {                                                                        \
    _Pragma("unroll") for (int ks = 0; ks < 8; ++ks)                          \
        *(v4u*)(ybuf + sbase + ks * 256) = SRC[ks];                           \
  } while (0)

  v4u s[8];
  LOADY(s, 0);
  STAGE_WR(s);

  f32x16v Oacc[4];
#pragma unroll
  for (int i = 0; i < 4; ++i)
#pragma unroll
    for (int j = 0; j < 16; ++j) Oacc[i][j] = 0.0f;

  float m_run = -__builtin_inff();
  float l_run = 0.0f;
  const unsigned ylds = (unsigned)(uintptr_t)&ybuf[0];
  constexpr float L2E = 1.44269504088896f;

  v2u trr[16];

#define ISSUE_TR()                                                            \
  do {                                                                        \
    _Pragma("unroll") for (int kb = 0; kb < 2; ++kb)                          \
        _Pragma("unroll") for (int df = 0; df < 4; ++df) {                    \
      const unsigned wb =                                                     \
          ylds + (unsigned)((kb * 4 + g2 * 2) * 8192 +                        \
                            ((w * 4 + df) * 2 + (l31 >> 4)) * 128 +           \
                            (l31 & 15) * 8);                                  \
      asm volatile("ds_read_b64_tr_b16 %0, %1"                                \
                   : "=v"(trr[kb * 8 + df * 2])                               \
                   : "v"(wb));                                                \
      asm volatile("ds_read_b64_tr_b16 %0, %1"                                \
                   : "=v"(trr[kb * 8 + df * 2 + 1])                           \
                   : "v"(wb + 8192u));                                        \
    }                                                                         \
  } while (0)

  __syncthreads();

#define TILE_BODY(t_)                                                         \
  do {                                                                        \
    f32x4v acc0 = {0.f, 0.f, 0.f, 0.f}, acc1 = {0.f, 0.f, 0.f, 0.f};          \
    _Pragma("unroll") for (int ks = 0; ks < 8; ++ks) {                        \
      half8 av = __builtin_bit_cast(half8, s[ks]);                            \
      acc0 = __builtin_amdgcn_mfma_f32_16x16x32_f16(                          \
          av, __builtin_bit_cast(half8, qreg[0][ks]), acc0, 0, 0, 0);         \
      acc1 = __builtin_amdgcn_mfma_f32_16x16x32_f16(                          \
          av, __builtin_bit_cast(half8, qreg[1][ks]), acc1, 0, 0, 0);         \
    }                                                                         \
    LOADY(s, ((t_) + 1) & 63);                                                \
    *(f32x4v*)&pscr2[ds][lm][kvf * 16 + g * 4] = acc0;                        \
    *(f32x4v*)&pscr2[ds][16 + lm][kvf * 16 + g * 4] = acc1;                   \
    barrier_lgkm(); /* B1: partials + ybuf(t) visible */                      \
    if (w >= 2) {                                                             \
      ISSUE_TR();                                                             \
    } else {                                                                  \
      __builtin_amdgcn_s_setprio(1);                                          \
      const int rq = w * 16 + (l >> 2); /* global q row */                    \
      const int c = l & 3;              /* kv octet */                        \
      f32x4v lo = {0.f, 0.f, 0.f, 0.f}, hi = {0.f, 0.f, 0.f, 0.f};            \
      _Pragma("unroll") for (int s_ = 0; s_ < 4; ++s_) {                      \
        lo += *(const f32x4v*)&pscr2[s_][rq][c * 8];                          \
        hi += *(const f32x4v*)&pscr2[s_][rq][c * 8 + 4];                      \
      }                                                                       \
      float pm = fmaxf(fmaxf(fmaxf(lo[0], lo[1]), fmaxf(lo[2], lo[3])),       \
                       fmaxf(fmaxf(hi[0], hi[1]), fmaxf(hi[2], hi[3])));      \
      pm = quad_max(pm);                                                      \
      bool defer = (pm <= m_run + 8.0f);                                      \
      bool allw = (bool)__all((int)defer);                                    \
      float scale = 1.0f;                                                     \
      if (!allw) {                                                            \
        float mn = fmaxf(m_run, pm);                                          \
        scale = fast_exp2((m_run - mn) * L2E);                                \
        m_run = mn;                                                           \
      }                                                                       \
      f32x4v ea, eb;                                                          \
      _Pragma("unroll") for (int i = 0; i < 4; ++i) {                         \
        ea[i] = fast_exp2((lo[i] - m_run) * L2E);                             \
        eb[i] = fast_exp2((hi[i] - m_run) * L2E);                             \
      }                                                                       \
      float ps = (ea[0] + ea[1]) + (ea[2] + ea[3]) + (eb[0] + eb[1]) +        \
                 (eb[2] + eb[3]);                                             \
      ps = quad_add(ps);                                                      \
      l_run = l_run * scale + ps;                                             \
      v4u pk;                                                                 \
      pk[0] = cvt2(ea[0], ea[1]);                                             \
      pk[1] = cvt2(ea[2], ea[3]);                                             \
      pk[2] = cvt2(eb[0], eb[1]);                                             \
      pk[3] = cvt2(eb[2], eb[3]);                                             \
      *(v4u*)(Pb + c * 512 + rq * 16) = pk;                                   \
      if (c == 0) sscale[rq] = scale;                                         \
      if (l == 0) sflag[w] = allw ? 0 : 1;                                    \
      __builtin_amdgcn_s_setprio(0);                                          \
      ISSUE_TR();                                                             \
    }                                                                         \
    barrier_lgkm(); /* B2: P + stats visible; tr data in regs */              \
    half8 pa0 = *(const half8*)(Pb + g2 * 512 + l31 * 16);                    \
    half8 pa1 = *(const half8*)(Pb + (2 + g2) * 512 + l31 * 16);              \
    if (sflag[0] | sflag[1]) {                                                \
      _Pragma("unroll") for (int df = 0; df < 4; ++df)                        \
          _Pragma("unroll") for (int r = 0; r < 16; ++r) {                    \
        const int q_ = (r & 3) + 8 * (r >> 2) + 4 * g2;                       \
        Oacc[df][r] *= sscale[q_];                                            \
      }                                                                       \
    }                                                                         \
    asm volatile("s_waitcnt lgkmcnt(0)" ::: "memory");                        \
    __builtin_amdgcn_sched_barrier(0);                                        \
    _Pragma("unroll") for (int kb = 0; kb < 2; ++kb)                          \
        _Pragma("unroll") for (int df = 0; df < 4; ++df) {                    \
      v4u bu;                                                                 \
      bu[0] = trr[kb * 8 + df * 2][0];                                        \
      bu[1] = trr[kb * 8 + df * 2][1];                                        \
      bu[2] = trr[kb * 8 + df * 2 + 1][0];                                    \
      bu[3] = trr[kb * 8 + df * 2 + 1][1];                                    \
      Oacc[df] = __builtin_amdgcn_mfma_f32_32x32x16_f16(                      \
          kb ? pa1 : pa0, __builtin_bit_cast(half8, bu), Oacc[df], 0, 0, 0);  \
    }                                                                         \
    barrier_plain(); /* B3: PV/pscr/Pb reads done, ybuf free */               \
    STAGE_WR(s);                                                              \
  } while (0)

  for (int t = 0; t < NT; ++t) {
    TILE_BODY(t);
  }

  // ---- epilogue
  if (w < 2 && (l & 3) == 0) sinvl[w * 16 + (l >> 2)] = 1.0f / l_run;
  __syncthreads();
#pragma unroll
  for (int df = 0; df < 4; ++df)
#pragma unroll
    for (int r = 0; r < 16; ++r) {
      const int q_ = (r & 3) + 8 * (r >> 2) + 4 * g2;
      const float inv = sinvl[q_];
      Om[(size_t)(bY + row0 + q_) * Dd + (w * 4 + df) * 32 + l31] =
          Oacc[df][r] * inv;
    }
#undef TILE_BODY
#undef ISSUE_TR
#undef STAGE_WR
#undef LOADY
}

}  // namespace

extern "C" void kernel_launch(void* const* d_in, const int* in_sizes, int n_in,
                              void* d_out, int out_size, void* d_ws,
                              size_t ws_size, hipStream_t stream) {
  (void)in_sizes; (void)n_in; (void)out_size;
  const float* x = (const float*)d_in[0];
  const float* y = (const float*)d_in[1];
  float* A = (float*)d_out;
  float* Bo = A + (size_t)Bb * Nn * Dd;
  const size_t halfws = (size_t)Bb * Nn * Dd * 2;  // 32 MiB per matrix
  dim3 fg(512), fb(512);
  if (d_ws != nullptr && ws_size >= 2 * halfws) {
    v4u* Xw = (v4u*)d_ws;
    v4u* Yw = (v4u*)((char*)d_ws + halfws);
    hipLaunchKernelGGL(convf16, dim3(2048), dim3(256), 0, stream, x, Xw);
    hipLaunchKernelGGL(convf16, dim3(2048), dim3(256), 0, stream, y, Yw);
    hipLaunchKernelGGL(flash_fwd<1>, fg, fb, 0, stream, x, y, Xw, Yw, A);
    hipLaunchKernelGGL(flash_fwd<1>, fg, fb, 0, stream, y, x, Yw, Xw, Bo);
  } else {
    hipLaunchKernelGGL(flash_fwd<0>, fg, fb, 0, stream, x, y, (const v4u*)x,
                       (const v4u*)y, A);
    hipLaunchKernelGGL(flash_fwd<0>, fg, fb, 0, stream, y, x, (const v4u*)y,
                       (const v4u*)x, Bo);
  }
}